// Round 4
// baseline (524.076 us; speedup 1.0000x reference)
//
#include <hip/hip_runtime.h>
#include <stdint.h>

typedef __attribute__((ext_vector_type(8))) short short8;
typedef __attribute__((ext_vector_type(4))) float floatx4;

#define B_   8
#define H_   16
#define N_   1024
#define D_   64
#define NH_  (B_*H_)
#define LOG2E 1.44269504088896340736f

extern "C" {
__device__ float __ocml_native_exp2_f32(float);
__device__ float __ocml_native_rsqrt_f32(float);
}

// pack two f32 -> bf16x2 (round-half-up on magnitude; fine for our ranges)
__device__ __forceinline__ unsigned int pk2(float a, float b) {
    unsigned int ua = __float_as_uint(a) + 0x8000u;
    unsigned int ub = __float_as_uint(b) + 0x8000u;
    return __builtin_amdgcn_perm(ub, ua, 0x07060302);  // (bf(b)<<16)|bf(a)
}

// ---------------------------------------------------------------------------
// Fully fused cosine attention.
// R4: back to the wave=32-query structure (best LDS-reuse per MFMA) at the
// proven spill-free (512,4) compile point; setprio REMOVED (suspected
// regression: barrier-locked waves, m190 precedent); NEW: 2-deep register
// prefetch (named buffers A/B, statically indexed) so each stage() consumes
// loads issued ~1.5 chunks earlier -> global latency fully hidden, waitcnt
// becomes a counted vmcnt naturally.
// 512 threads = 8 waves; wave = 32 queries (2 m-tiles); block = 256 queries;
// grid = 128 heads * 4 (XCD-swizzled) -> 2 blocks/CU, 16 waves/CU (4/SIMD).
// LDS: stride-64-short rows, XOR swizzle cb^(row&7) on 16B blocks, all
// accesses 16B-aligned b128 (uniform 8 lanes / 16B window = full LDS BW).
//   ks[key][d] : K chunk bf16, row-normalized
//   vt[d][key] : V chunk transposed, key order permuted by
//                L(cb,j) = (cb>>2)*32 + (cb&3)*4 + (j>>2)*16 + (j&3)
// S^T = K.Qn^T via MFMA so exp(S^T) is directly the PV A-fragment.
// ---------------------------------------------------------------------------
__global__ __launch_bounds__(512, 4) void attn_fused(
    const float* __restrict__ q, const float* __restrict__ k,
    const float* __restrict__ v, float* __restrict__ out)
{
    __shared__ __align__(16) unsigned short ks[2][64 * 64];
    __shared__ __align__(16) unsigned short vt[2][64 * 64];

    const int bid = blockIdx.x;
    const int xcd = bid & 7, rest = bid >> 3;
    const int qt = rest & 3;
    const int head = (rest >> 2) * 8 + xcd;    // 4 blocks of a head share an XCD
    const int tid = threadIdx.x, w = tid >> 6, lane = tid & 63;
    const int lam = lane & 15, quad = lane >> 4;
    const int sw = lam & 7;                    // frag-read swizzle key
    const int q0 = qt * 256 + w * 32;          // this wave's 32 queries

    const float* qh = q + ((size_t)head * N_ + q0) * D_;
    const float* kh = k + (size_t)head * N_ * D_;
    const float* vh = v + (size_t)head * N_ * D_;

    // ---- Q: load f32, L2-normalize (x log2e), pack to bf16 B-frags ----
    short8 aq[2][2];
    #pragma unroll
    for (int t = 0; t < 2; t++) {
        const float* qr = qh + (t * 16 + lam) * D_ + quad * 8;
        float4 f0 = *(const float4*)(qr);
        float4 f1 = *(const float4*)(qr + 4);
        float4 f2 = *(const float4*)(qr + 32);
        float4 f3 = *(const float4*)(qr + 36);
        float ss = f0.x*f0.x + f0.y*f0.y + f0.z*f0.z + f0.w*f0.w
                 + f1.x*f1.x + f1.y*f1.y + f1.z*f1.z + f1.w*f1.w
                 + f2.x*f2.x + f2.y*f2.y + f2.z*f2.z + f2.w*f2.w
                 + f3.x*f3.x + f3.y*f3.y + f3.z*f3.z + f3.w*f3.w;
        ss += __shfl_xor(ss, 16);      // 4 quads of same lam cover dims 0..63
        ss += __shfl_xor(ss, 32);
        float sc = LOG2E * __ocml_native_rsqrt_f32(ss);
        union { unsigned int u[4]; short8 s8; } p0, p1;
        p0.u[0] = pk2(f0.x*sc, f0.y*sc); p0.u[1] = pk2(f0.z*sc, f0.w*sc);
        p0.u[2] = pk2(f1.x*sc, f1.y*sc); p0.u[3] = pk2(f1.z*sc, f1.w*sc);
        p1.u[0] = pk2(f2.x*sc, f2.y*sc); p1.u[1] = pk2(f2.z*sc, f2.w*sc);
        p1.u[2] = pk2(f3.x*sc, f3.y*sc); p1.u[3] = pk2(f3.z*sc, f3.w*sc);
        aq[t][0] = p0.s8; aq[t][1] = p1.s8;
    }

    floatx4 oacc[2][4];
    #pragma unroll
    for (int t = 0; t < 2; t++)
        #pragma unroll
        for (int dt = 0; dt < 4; dt++) oacc[t][dt] = (floatx4){0.f, 0.f, 0.f, 0.f};
    float l[2] = {0.f, 0.f};

    // ---- staging maps (512 threads stage one 64-key chunk) ----
    // K: thread owns key-row srow, 8 dims at d-block cbk = lane&7
    const int srow = w * 8 + (lane >> 3);
    const int cbk  = lane & 7;
    const int ksw  = srow & 7;
    // V^T: thread owns d = lane, phys key-block cb = w (8 logical keys)
    const int Lb   = ((w >> 2) << 5) + ((w & 3) << 2);   // L(w, 0)
    const int vwin = (w ^ (lane & 7)) << 3;

    // two named prefetch buffers (statically indexed -> stay in VGPRs)
    float4 kxa[2], kxb[2];
    float  vra[8], vrb[8];

    auto gload = [&](int ck, float4* kx, float* vr) {
        const float* kp = kh + ((size_t)(ck * 64 + srow)) * D_ + cbk * 8;
        kx[0] = *(const float4*)(kp);
        kx[1] = *(const float4*)(kp + 4);
        #pragma unroll
        for (int j = 0; j < 8; j++) {
            int L = Lb + ((j >> 2) << 4) + (j & 3);
            vr[j] = vh[((size_t)(ck * 64 + L)) * D_ + lane];   // coalesced b32
        }
    };

    auto stage = [&](int buf, const float4* kx, const float* vr) {
        float ss = kx[0].x*kx[0].x + kx[0].y*kx[0].y + kx[0].z*kx[0].z + kx[0].w*kx[0].w
                 + kx[1].x*kx[1].x + kx[1].y*kx[1].y + kx[1].z*kx[1].z + kx[1].w*kx[1].w;
        ss += __shfl_xor(ss, 1);       // 8 lanes of same key cover dims 0..63
        ss += __shfl_xor(ss, 2);
        ss += __shfl_xor(ss, 4);
        float sc = __ocml_native_rsqrt_f32(ss);
        union { unsigned int u[4]; short8 s8; } pk;
        pk.u[0] = pk2(kx[0].x*sc, kx[0].y*sc); pk.u[1] = pk2(kx[0].z*sc, kx[0].w*sc);
        pk.u[2] = pk2(kx[1].x*sc, kx[1].y*sc); pk.u[3] = pk2(kx[1].z*sc, kx[1].w*sc);
        *(short8*)&ks[buf][srow * 64 + ((cbk ^ ksw) << 3)] = pk.s8;      // b128
        union { unsigned int u[4]; short8 s8; } pv;
        pv.u[0] = pk2(vr[0], vr[1]); pv.u[1] = pk2(vr[2], vr[3]);
        pv.u[2] = pk2(vr[4], vr[5]); pv.u[3] = pk2(vr[6], vr[7]);
        *(short8*)&vt[buf][lane * 64 + vwin] = pv.s8;                    // b128
    };

    auto compute = [&](int buf) {
        const unsigned short* ksb = &ks[buf][0];
        const unsigned short* vsb = &vt[buf][0];
        #pragma unroll
        for (int g = 0; g < 2; g++) {
            // ---- S^T for 32 keys: A = K-frag (LDS b128), B = Q-frag (regs) ----
            floatx4 s[2][2];
            #pragma unroll
            for (int s2 = 0; s2 < 2; s2++) {
                int st = g * 2 + s2;
                short8 bk0 = *(const short8*)(ksb + (st * 16 + lam) * 64 + (((0 + quad) ^ sw) << 3));
                short8 bk1 = *(const short8*)(ksb + (st * 16 + lam) * 64 + (((4 + quad) ^ sw) << 3));
                #pragma unroll
                for (int t = 0; t < 2; t++) {
                    floatx4 acc = (floatx4){0.f, 0.f, 0.f, 0.f};
                    acc = __builtin_amdgcn_mfma_f32_16x16x32_bf16(bk0, aq[t][0], acc, 0, 0, 0);
                    acc = __builtin_amdgcn_mfma_f32_16x16x32_bf16(bk1, aq[t][1], acc, 0, 0, 0);
                    s[t][s2] = acc;
                }
            }
            // ---- exp2 + pack: S^T C-layout IS the PV A-fragment layout ----
            short8 pa[2];
            #pragma unroll
            for (int t = 0; t < 2; t++) {
                float e00 = __ocml_native_exp2_f32(s[t][0][0]);
                float e01 = __ocml_native_exp2_f32(s[t][0][1]);
                float e02 = __ocml_native_exp2_f32(s[t][0][2]);
                float e03 = __ocml_native_exp2_f32(s[t][0][3]);
                float e10 = __ocml_native_exp2_f32(s[t][1][0]);
                float e11 = __ocml_native_exp2_f32(s[t][1][1]);
                float e12 = __ocml_native_exp2_f32(s[t][1][2]);
                float e13 = __ocml_native_exp2_f32(s[t][1][3]);
                l[t] += ((e00 + e01) + (e02 + e03)) + ((e10 + e11) + (e12 + e13));
                union { unsigned int u[4]; short8 s8; } pk;
                pk.u[0] = pk2(e00, e01); pk.u[1] = pk2(e02, e03);
                pk.u[2] = pk2(e10, e11); pk.u[3] = pk2(e12, e13);
                pa[t] = pk.s8;
            }
            // ---- PV: B-frag = one b128 from vt (permuted V^T) ----
            #pragma unroll
            for (int dt = 0; dt < 4; dt++) {
                short8 bv = *(const short8*)(vsb + (dt * 16 + lam) * 64 + (((g * 4 + quad) ^ sw) << 3));
                #pragma unroll
                for (int t = 0; t < 2; t++)
                    oacc[t][dt] = __builtin_amdgcn_mfma_f32_16x16x32_bf16(pa[t], bv, oacc[t][dt], 0, 0, 0);
            }
        }
    };

    // ---- 2-deep prefetch pipeline: stage(c) consumes loads issued ~1.5
    //      chunks earlier; 1 barrier per chunk; buffers named statically ----
    gload(0, kxa, vra);
    gload(1, kxb, vrb);
    stage(0, kxa, vra);
    __syncthreads();
    for (int cc = 0; cc < 8; ++cc) {
        const int c0 = cc * 2;                     // even chunk in lds0/kxa slot
        if (c0 + 2 < 16) gload(c0 + 2, kxa, vra);  // kxa's old chunk already staged
        compute(0);
        stage(1, kxb, vrb);                        // chunk c0+1 (loaded last iter)
        __syncthreads();
        if (c0 + 3 < 16) gload(c0 + 3, kxb, vrb);
        compute(1);
        if (c0 + 2 < 16) stage(0, kxa, vra);       // chunk c0+2 (loaded this iter)
        __syncthreads();
    }

    // ---- epilogue: reduce l across quads, divide, store f32 ----
    const int b = head >> 4, hh = head & 15;
    #pragma unroll
    for (int t = 0; t < 2; t++) {
        float lr = l[t];
        lr += __shfl_xor(lr, 16);
        lr += __shfl_xor(lr, 32);
        float rl = 1.0f / lr;                    // lane lam holds 1/l for query t*16+lam
        float rq[4];
        #pragma unroll
        for (int r = 0; r < 4; r++) rq[r] = __shfl(rl, quad * 4 + r);
        float* ob = out + ((size_t)b * N_ + q0 + t * 16) * (H_ * D_) + hh * 64;
        #pragma unroll
        for (int dt = 0; dt < 4; dt++)
            #pragma unroll
            for (int r = 0; r < 4; r++)
                ob[(quad * 4 + r) * (H_ * D_) + dt * 16 + lam] = oacc[t][dt][r] * rq[r];
    }
}

extern "C" void kernel_launch(void* const* d_in, const int* in_sizes, int n_in,
                              void* d_out, int out_size, void* d_ws, size_t ws_size,
                              hipStream_t stream) {
    const float* q = (const float*)d_in[0];
    const float* k = (const float*)d_in[1];
    const float* v = (const float*)d_in[2];
    float* out = (float*)d_out;
    (void)d_ws; (void)ws_size;
    hipLaunchKernelGGL(attn_fused, dim3(NH_ * 4), dim3(512), 0, stream, q, k, v, out);
}

// Round 5
// 160.751 us; speedup vs baseline: 3.2602x; 3.2602x over previous
//
#include <hip/hip_runtime.h>
#include <stdint.h>

typedef __attribute__((ext_vector_type(8))) short short8;
typedef __attribute__((ext_vector_type(4))) float floatx4;

#define B_   8
#define H_   16
#define N_   1024
#define D_   64
#define NH_  (B_*H_)
#define LOG2E 1.44269504088896340736f

extern "C" {
__device__ float __ocml_native_exp2_f32(float);
__device__ float __ocml_native_rsqrt_f32(float);
}

// pack two f32 -> bf16x2 (round-half-up on magnitude; fine for our ranges)
__device__ __forceinline__ unsigned int pk2(float a, float b) {
    unsigned int ua = __float_as_uint(a) + 0x8000u;
    unsigned int ub = __float_as_uint(b) + 0x8000u;
    return __builtin_amdgcn_perm(ub, ua, 0x07060302);  // (bf(b)<<16)|bf(a)
}

// ---------------------------------------------------------------------------
// Fully fused cosine attention.
// R5: exact restore of the prior-session best (159.1 us harness): R1 minus
// ALL setprio. Clean A/B vs R1 (108 us rocprof) isolating setprio, which is
// suspected of a ~35% regression (barrier-locked waves: prio(1) compute
// waves starve co-resident waves' stage(), the critical path to the next
// barrier; m190 precedent). kx/vr captured by reference (proven in-register,
// VGPR=64, no scratch — R4's pointer-arg variant spilled 1.6 GB).
// 512 threads = 8 waves; wave = 32 queries (2 m-tiles); block = 256 queries;
// grid = 128 heads * 4 (XCD-swizzled) -> 2 blocks/CU, 16 waves/CU (4/SIMD).
// LDS: stride-64-short rows, XOR swizzle cb^(row&7) on 16B blocks, all
// accesses 16B-aligned b128 (uniform 8 lanes / 16B window = full LDS BW).
//   ks[key][d] : K chunk bf16, row-normalized
//   vt[d][key] : V chunk transposed, key order permuted by
//                L(cb,j) = (cb>>2)*32 + (cb&3)*4 + (j>>2)*16 + (j&3)
// S^T = K.Qn^T via MFMA so exp(S^T) is directly the PV A-fragment.
// ---------------------------------------------------------------------------
__global__ __launch_bounds__(512, 4) void attn_fused(
    const float* __restrict__ q, const float* __restrict__ k,
    const float* __restrict__ v, float* __restrict__ out)
{
    __shared__ __align__(16) unsigned short ks[2][64 * 64];
    __shared__ __align__(16) unsigned short vt[2][64 * 64];

    const int bid = blockIdx.x;
    const int xcd = bid & 7, rest = bid >> 3;
    const int qt = rest & 3;
    const int head = (rest >> 2) * 8 + xcd;    // 4 blocks of a head share an XCD
    const int tid = threadIdx.x, w = tid >> 6, lane = tid & 63;
    const int lam = lane & 15, quad = lane >> 4;
    const int sw = lam & 7;                    // frag-read swizzle key
    const int q0 = qt * 256 + w * 32;          // this wave's 32 queries

    const float* qh = q + ((size_t)head * N_ + q0) * D_;
    const float* kh = k + (size_t)head * N_ * D_;
    const float* vh = v + (size_t)head * N_ * D_;

    // ---- Q: load f32, L2-normalize (x log2e), pack to bf16 B-frags ----
    short8 aq[2][2];
    #pragma unroll
    for (int t = 0; t < 2; t++) {
        const float* qr = qh + (t * 16 + lam) * D_ + quad * 8;
        float4 f0 = *(const float4*)(qr);
        float4 f1 = *(const float4*)(qr + 4);
        float4 f2 = *(const float4*)(qr + 32);
        float4 f3 = *(const float4*)(qr + 36);
        float ss = f0.x*f0.x + f0.y*f0.y + f0.z*f0.z + f0.w*f0.w
                 + f1.x*f1.x + f1.y*f1.y + f1.z*f1.z + f1.w*f1.w
                 + f2.x*f2.x + f2.y*f2.y + f2.z*f2.z + f2.w*f2.w
                 + f3.x*f3.x + f3.y*f3.y + f3.z*f3.z + f3.w*f3.w;
        ss += __shfl_xor(ss, 16);      // 4 quads of same lam cover dims 0..63
        ss += __shfl_xor(ss, 32);
        float sc = LOG2E * __ocml_native_rsqrt_f32(ss);
        union { unsigned int u[4]; short8 s8; } p0, p1;
        p0.u[0] = pk2(f0.x*sc, f0.y*sc); p0.u[1] = pk2(f0.z*sc, f0.w*sc);
        p0.u[2] = pk2(f1.x*sc, f1.y*sc); p0.u[3] = pk2(f1.z*sc, f1.w*sc);
        p1.u[0] = pk2(f2.x*sc, f2.y*sc); p1.u[1] = pk2(f2.z*sc, f2.w*sc);
        p1.u[2] = pk2(f3.x*sc, f3.y*sc); p1.u[3] = pk2(f3.z*sc, f3.w*sc);
        aq[t][0] = p0.s8; aq[t][1] = p1.s8;
    }

    floatx4 oacc[2][4];
    #pragma unroll
    for (int t = 0; t < 2; t++)
        #pragma unroll
        for (int dt = 0; dt < 4; dt++) oacc[t][dt] = (floatx4){0.f, 0.f, 0.f, 0.f};
    float l[2] = {0.f, 0.f};

    // ---- staging maps (512 threads stage one 64-key chunk) ----
    // K: thread owns key-row srow, 8 dims at d-block cbk = lane&7
    const int srow = w * 8 + (lane >> 3);
    const int cbk  = lane & 7;
    const int ksw  = srow & 7;
    // V^T: thread owns d = lane, phys key-block cb = w (8 logical keys)
    const int Lb   = ((w >> 2) << 5) + ((w & 3) << 2);   // L(w, 0)
    const int vwin = (w ^ (lane & 7)) << 3;

    float4 kx[2];
    float  vr[8];

    auto gload = [&](int ck) {
        const float* kp = kh + ((size_t)(ck * 64 + srow)) * D_ + cbk * 8;
        kx[0] = *(const float4*)(kp);
        kx[1] = *(const float4*)(kp + 4);
        #pragma unroll
        for (int j = 0; j < 8; j++) {
            int L = Lb + ((j >> 2) << 4) + (j & 3);
            vr[j] = vh[((size_t)(ck * 64 + L)) * D_ + lane];   // coalesced b32
        }
    };

    auto stage = [&](int buf) {
        float ss = kx[0].x*kx[0].x + kx[0].y*kx[0].y + kx[0].z*kx[0].z + kx[0].w*kx[0].w
                 + kx[1].x*kx[1].x + kx[1].y*kx[1].y + kx[1].z*kx[1].z + kx[1].w*kx[1].w;
        ss += __shfl_xor(ss, 1);       // 8 lanes of same key cover dims 0..63
        ss += __shfl_xor(ss, 2);
        ss += __shfl_xor(ss, 4);
        float sc = __ocml_native_rsqrt_f32(ss);
        union { unsigned int u[4]; short8 s8; } pk;
        pk.u[0] = pk2(kx[0].x*sc, kx[0].y*sc); pk.u[1] = pk2(kx[0].z*sc, kx[0].w*sc);
        pk.u[2] = pk2(kx[1].x*sc, kx[1].y*sc); pk.u[3] = pk2(kx[1].z*sc, kx[1].w*sc);
        *(short8*)&ks[buf][srow * 64 + ((cbk ^ ksw) << 3)] = pk.s8;      // b128
        union { unsigned int u[4]; short8 s8; } pv;
        pv.u[0] = pk2(vr[0], vr[1]); pv.u[1] = pk2(vr[2], vr[3]);
        pv.u[2] = pk2(vr[4], vr[5]); pv.u[3] = pk2(vr[6], vr[7]);
        *(short8*)&vt[buf][lane * 64 + vwin] = pv.s8;                    // b128
    };

    auto compute = [&](int buf) {
        const unsigned short* ksb = &ks[buf][0];
        const unsigned short* vsb = &vt[buf][0];
        #pragma unroll
        for (int g = 0; g < 2; g++) {
            // ---- S^T for 32 keys: A = K-frag (LDS b128), B = Q-frag (regs) ----
            floatx4 s[2][2];
            #pragma unroll
            for (int s2 = 0; s2 < 2; s2++) {
                int st = g * 2 + s2;
                short8 bk0 = *(const short8*)(ksb + (st * 16 + lam) * 64 + (((0 + quad) ^ sw) << 3));
                short8 bk1 = *(const short8*)(ksb + (st * 16 + lam) * 64 + (((4 + quad) ^ sw) << 3));
                #pragma unroll
                for (int t = 0; t < 2; t++) {
                    floatx4 acc = (floatx4){0.f, 0.f, 0.f, 0.f};
                    acc = __builtin_amdgcn_mfma_f32_16x16x32_bf16(bk0, aq[t][0], acc, 0, 0, 0);
                    acc = __builtin_amdgcn_mfma_f32_16x16x32_bf16(bk1, aq[t][1], acc, 0, 0, 0);
                    s[t][s2] = acc;
                }
            }
            // ---- exp2 + pack: S^T C-layout IS the PV A-fragment layout ----
            short8 pa[2];
            #pragma unroll
            for (int t = 0; t < 2; t++) {
                float e00 = __ocml_native_exp2_f32(s[t][0][0]);
                float e01 = __ocml_native_exp2_f32(s[t][0][1]);
                float e02 = __ocml_native_exp2_f32(s[t][0][2]);
                float e03 = __ocml_native_exp2_f32(s[t][0][3]);
                float e10 = __ocml_native_exp2_f32(s[t][1][0]);
                float e11 = __ocml_native_exp2_f32(s[t][1][1]);
                float e12 = __ocml_native_exp2_f32(s[t][1][2]);
                float e13 = __ocml_native_exp2_f32(s[t][1][3]);
                l[t] += ((e00 + e01) + (e02 + e03)) + ((e10 + e11) + (e12 + e13));
                union { unsigned int u[4]; short8 s8; } pk;
                pk.u[0] = pk2(e00, e01); pk.u[1] = pk2(e02, e03);
                pk.u[2] = pk2(e10, e11); pk.u[3] = pk2(e12, e13);
                pa[t] = pk.s8;
            }
            // ---- PV: B-frag = one b128 from vt (permuted V^T) ----
            #pragma unroll
            for (int dt = 0; dt < 4; dt++) {
                short8 bv = *(const short8*)(vsb + (dt * 16 + lam) * 64 + (((g * 4 + quad) ^ sw) << 3));
                #pragma unroll
                for (int t = 0; t < 2; t++)
                    oacc[t][dt] = __builtin_amdgcn_mfma_f32_16x16x32_bf16(pa[t], bv, oacc[t][dt], 0, 0, 0);
            }
        }
    };

    // ---- software-pipelined chunk loop: 1 barrier per chunk ----
    gload(0);
    stage(0);
    __syncthreads();
    for (int c = 0; c < 16; ++c) {
        int buf = c & 1;
        if (c < 15) gload(c + 1);      // regs prefetch overlaps compute
        compute(buf);
        if (c < 15) stage(buf ^ 1);    // waits on prefetch, writes other buffer
        __syncthreads();
    }

    // ---- epilogue: reduce l across quads, divide, store f32 ----
    const int b = head >> 4, hh = head & 15;
    #pragma unroll
    for (int t = 0; t < 2; t++) {
        float lr = l[t];
        lr += __shfl_xor(lr, 16);
        lr += __shfl_xor(lr, 32);
        float rl = 1.0f / lr;                    // lane lam holds 1/l for query t*16+lam
        float rq[4];
        #pragma unroll
        for (int r = 0; r < 4; r++) rq[r] = __shfl(rl, quad * 4 + r);
        float* ob = out + ((size_t)b * N_ + q0 + t * 16) * (H_ * D_) + hh * 64;
        #pragma unroll
        for (int dt = 0; dt < 4; dt++)
            #pragma unroll
            for (int r = 0; r < 4; r++)
                ob[(quad * 4 + r) * (H_ * D_) + dt * 16 + lam] = oacc[t][dt][r] * rq[r];
    }
}

extern "C" void kernel_launch(void* const* d_in, const int* in_sizes, int n_in,
                              void* d_out, int out_size, void* d_ws, size_t ws_size,
                              hipStream_t stream) {
    const float* q = (const float*)d_in[0];
    const float* k = (const float*)d_in[1];
    const float* v = (const float*)d_in[2];
    float* out = (float*)d_out;
    (void)d_ws; (void)ws_size;
    hipLaunchKernelGGL(attn_fused, dim3(NH_ * 4), dim3(512), 0, stream, q, k, v, out);
}